// Round 1
// baseline (31.995 us; speedup 1.0000x reference)
//
#include <hip/hip_runtime.h>
#include <math.h>

#define NB 256          // batch
#define NT 4            // task dim
#define NTL 65536       // T*L flattened per sample
#define CHUNKS 8        // blocks per sample
#define CHUNK_ELEMS (NTL / CHUNKS)   // 8192
#define BLOCK 256
#define V4_PER_THREAD (CHUNK_ELEMS / 4 / BLOCK)  // 8 float4 iters/thread

// lgamma(x+1) for non-negative integer-valued x (data is 0..4); general fallback.
__device__ __forceinline__ float lgfact(float x) {
  if (x < 1.5f) return 0.0f;                       // 0!, 1!
  if (x < 2.5f) return 0.69314718055994531f;       // ln 2
  if (x < 3.5f) return 1.79175946922805500f;       // ln 6
  if (x < 4.5f) return 3.17805383034794562f;       // ln 24
  if (x < 5.5f) return 4.78749174278204599f;       // ln 120
  if (x < 6.5f) return 6.57925121201010100f;       // ln 720
  if (x < 7.5f) return 8.52516136106541430f;       // ln 5040
  return lgammaf(x + 1.0f);
}

__global__ __launch_bounds__(BLOCK) void nll_partials(
    const float* __restrict__ logits,
    const float* __restrict__ xcnt,
    float* __restrict__ ws)
{
  const int blk = blockIdx.x;
  const int b = blk / CHUNKS;
  const int c = blk % CHUNKS;
  const int t = threadIdx.x;
  const size_t base = (size_t)b * NTL + (size_t)c * CHUNK_ELEMS;
  const float4* __restrict__ l4 = (const float4*)(logits + base);
  const float4* __restrict__ x4 = (const float4*)(xcnt + base);

  float m = -INFINITY, s = 0.f, dot = 0.f, sx = 0.f, slg = 0.f;
#pragma unroll
  for (int k = 0; k < V4_PER_THREAD; ++k) {
    const float4 l = l4[t + k * BLOCK];
    const float4 x = x4[t + k * BLOCK];
    // online logsumexp: one rescale per float4
    const float m4 = fmaxf(fmaxf(l.x, l.y), fmaxf(l.z, l.w));
    const float nm = fmaxf(m, m4);
    s = s * __expf(m - nm)
      + __expf(l.x - nm) + __expf(l.y - nm)
      + __expf(l.z - nm) + __expf(l.w - nm);
    m = nm;
    dot = fmaf(x.x, l.x, dot);
    dot = fmaf(x.y, l.y, dot);
    dot = fmaf(x.z, l.z, dot);
    dot = fmaf(x.w, l.w, dot);
    sx += (x.x + x.y) + (x.z + x.w);
    slg += (lgfact(x.x) + lgfact(x.y)) + (lgfact(x.z) + lgfact(x.w));
  }

  // 64-lane butterfly reduce (all-lanes-valid, no out-of-range reads)
#pragma unroll
  for (int off = 32; off >= 1; off >>= 1) {
    const float m2 = __shfl_xor(m, off);
    const float s2 = __shfl_xor(s, off);
    const float nm = fmaxf(m, m2);
    s = s * __expf(m - nm) + s2 * __expf(m2 - nm);
    m = nm;
    dot += __shfl_xor(dot, off);
    sx  += __shfl_xor(sx,  off);
    slg += __shfl_xor(slg, off);
  }

  __shared__ float sm[4], ss[4], sdot[4], ssx[4], sslg[4];
  const int wid = t >> 6;
  if ((t & 63) == 0) { sm[wid] = m; ss[wid] = s; sdot[wid] = dot; ssx[wid] = sx; sslg[wid] = slg; }
  __syncthreads();
  if (t == 0) {
    float M = sm[0], S = ss[0], D = sdot[0], X = ssx[0], G = sslg[0];
#pragma unroll
    for (int w = 1; w < BLOCK / 64; ++w) {
      const float nm = fmaxf(M, sm[w]);
      S = S * __expf(M - nm) + ss[w] * __expf(sm[w] - nm);
      M = nm;
      D += sdot[w]; X += ssx[w]; G += sslg[w];
    }
    float* p = ws + (size_t)blk * 5;
    p[0] = M; p[1] = S; p[2] = D; p[3] = X; p[4] = G;
  }
}

__global__ __launch_bounds__(NB) void finalize(
    const float* __restrict__ pred_counts,
    const float* __restrict__ target_counts,
    const float* __restrict__ cw,
    const float* __restrict__ ws,
    float* __restrict__ out)
{
  const int b = threadIdx.x;  // one thread per sample

  float m = -INFINITY, s = 0.f, dot = 0.f, sx = 0.f, slg = 0.f;
#pragma unroll
  for (int c = 0; c < CHUNKS; ++c) {
    const float* p = ws + (size_t)(b * CHUNKS + c) * 5;
    const float m2 = p[0], s2 = p[1];
    const float nm = fmaxf(m, m2);
    s = s * __expf(m - nm) + s2 * __expf(m2 - nm);
    m = nm;
    dot += p[2]; sx += p[3]; slg += p[4];
  }
  const float n = sx;
  const float lse = m + logf(s);
  const float log_prob = lgammaf(n + 1.0f) - slg + dot - n * lse;

  float tt = 0.f, tp = 0.f;
#pragma unroll
  for (int j = 0; j < NT; ++j) {
    tt += target_counts[b * NT + j];
    tp += pred_counts[b * NT + j];
  }
  const float d = tt - tp;
  const float val = -log_prob + cw[0] * d * d;

  __shared__ float red[NB];
  red[b] = val;
  __syncthreads();
#pragma unroll
  for (int off = NB / 2; off >= 1; off >>= 1) {
    if (b < off) red[b] += red[b + off];
    __syncthreads();
  }
  if (b == 0) out[0] = red[0] * (1.0f / NB);
}

extern "C" void kernel_launch(void* const* d_in, const int* in_sizes, int n_in,
                              void* d_out, int out_size, void* d_ws, size_t ws_size,
                              hipStream_t stream) {
  const float* pred_counts   = (const float*)d_in[0];
  const float* target_counts = (const float*)d_in[1];
  const float* pred_prof     = (const float*)d_in[2];
  const float* target_prof   = (const float*)d_in[3];
  const float* cw            = (const float*)d_in[4];
  float* out = (float*)d_out;
  float* ws  = (float*)d_ws;   // needs NB*CHUNKS*5 floats = 40 KiB

  nll_partials<<<NB * CHUNKS, BLOCK, 0, stream>>>(pred_prof, target_prof, ws);
  finalize<<<1, NB, 0, stream>>>(pred_counts, target_counts, cw, ws, out);
}